// Round 6
// baseline (324.312 us; speedup 1.0000x reference)
//
#include <hip/hip_runtime.h>
#include <hip/hip_bf16.h>

#define N_NODES 100000
#define N_EDGES 800000
#define D 128
#define NH 8
#define NB ((N_NODES + 255) / 256)   // 391 scan blocks

typedef __hip_bfloat16 bf16;
typedef __bf16 bf16x8 __attribute__((ext_vector_type(8)));
typedef float  f32x4  __attribute__((ext_vector_type(4)));

__device__ __forceinline__ unsigned short f2bu(float x) {
    bf16 b = __float2bfloat16(x);
    return *reinterpret_cast<unsigned short*>(&b);
}
__device__ __forceinline__ float bu2f(unsigned short u) {
    return __uint_as_float(((unsigned)u) << 16);
}
__device__ __forceinline__ float bfe0(unsigned u) { return __uint_as_float(u << 16); }
__device__ __forceinline__ float bfe1(unsigned u) { return __uint_as_float(u & 0xffff0000u); }

// 8 packed bf16 (uint4) -> 8 f32
__device__ __forceinline__ void ext8(uint4 u, float* f) {
    f[0] = bfe0(u.x); f[1] = bfe1(u.x);
    f[2] = bfe0(u.y); f[3] = bfe1(u.y);
    f[4] = bfe0(u.z); f[5] = bfe1(u.z);
    f[6] = bfe0(u.w); f[7] = bfe1(u.w);
}

union frag_u { unsigned short u[8]; bf16x8 v; };

// ---------------------------------------------------------------------------
// Kernel 0: lay W out in MFMA B-fragment order, split into bf16 hi/lo.
// ---------------------------------------------------------------------------
__global__ __launch_bounds__(256) void wf_prep(
    const float* __restrict__ Wq, const float* __restrict__ Wk, const float* __restrict__ Wv,
    unsigned short* __restrict__ Wf)
{
    int t = blockIdx.x * 256 + threadIdx.x;   // over 3*32*64 = 6144
    if (t >= 3 * 32 * 64) return;
    int lane = t & 63;
    int ct   = (t >> 6) & 31;
    int mat  = t >> 11;
    const float* W = (mat == 0) ? Wq : (mat == 1) ? Wk : Wv;
    int c  = ct >> 3, tt = ct & 7;
    int n  = tt * 16 + (lane & 15);
    int kb = c * 32 + (lane >> 4) * 8;
    unsigned short* dst = Wf + (size_t)mat * 32768 + (size_t)ct * 1024 + (size_t)lane * 8;
#pragma unroll
    for (int j = 0; j < 8; ++j) {
        float w  = W[(size_t)(kb + j) * D + n];
        unsigned short hb = f2bu(w);
        float lo = w - bu2f(hb);
        dst[j]       = hb;          // hi (part 0)
        dst[512 + j] = f2bu(lo);    // lo (part 1)
    }
}

// ---------------------------------------------------------------------------
// Kernel 1: fused Q/K/V projection via bf16 MFMA with hi/lo precision split.
// Q -> Qb [N,128]; K,V -> interleaved KV [N,256] = [K 128 | V 128] so the
// edge phase gathers one contiguous 512 B row per edge.
// ---------------------------------------------------------------------------
__global__ __launch_bounds__(256) void qkv_mfma(
    const float* __restrict__ E, const unsigned short* __restrict__ Wf,
    bf16* __restrict__ Q, bf16* __restrict__ KV)
{
    __shared__ unsigned short bsh[16384];   // 32 KB: B staging, then epilogue
    const int tid  = threadIdx.x;
    const int wave = tid >> 6;
    const int lane = tid & 63;
    const int r0w  = blockIdx.x * 128 + wave * 32;   // this wave's 32 rows

    const int am = lane & 15;    // A row within 16-tile
    const int aq = lane >> 4;    // k quad

    // Load + split A fragments: 2 row-tiles x 4 k-chunks x 8 bf16 (hi/lo).
    frag_u ahi[2][4], alo[2][4];
#pragma unroll
    for (int rt = 0; rt < 2; ++rt) {
        int row = r0w + rt * 16 + am;
        if (row >= N_NODES) row = N_NODES - 1;     // clamp; stores are guarded
        const float* erow = E + (size_t)row * D + aq * 8;
#pragma unroll
        for (int c = 0; c < 4; ++c) {
            float4 e0 = *reinterpret_cast<const float4*>(erow + c * 32);
            float4 e1 = *reinterpret_cast<const float4*>(erow + c * 32 + 4);
            float ef[8] = {e0.x, e0.y, e0.z, e0.w, e1.x, e1.y, e1.z, e1.w};
#pragma unroll
            for (int j = 0; j < 8; ++j) {
                unsigned short hb = f2bu(ef[j]);
                ahi[rt][c].u[j] = hb;
                alo[rt][c].u[j] = f2bu(ef[j] - bu2f(hb));
            }
        }
    }

#pragma unroll
    for (int mat = 0; mat < 3; ++mat) {
        f32x4 acc[8][2];
#pragma unroll
        for (int t = 0; t < 8; ++t)
#pragma unroll
            for (int rt = 0; rt < 2; ++rt)
                acc[t][rt] = (f32x4){0.f, 0.f, 0.f, 0.f};

        const unsigned short* wm = Wf + (size_t)mat * 32768;

#pragma unroll
        for (int half = 0; half < 2; ++half) {
            __syncthreads();    // previous users of bsh are done
            const uint4* src = reinterpret_cast<const uint4*>(wm + half * 16384);
            uint4* dstv = reinterpret_cast<uint4*>(bsh);
#pragma unroll
            for (int k = 0; k < 8; ++k)
                dstv[k * 256 + tid] = src[k * 256 + tid];
            __syncthreads();

#pragma unroll
            for (int t = 0; t < 8; ++t) {
#pragma unroll
                for (int cc = 0; cc < 2; ++cc) {
                    const unsigned short* bp = bsh + (cc * 8 + t) * 1024 + lane * 8;
                    bf16x8 bhi = *reinterpret_cast<const bf16x8*>(bp);
                    bf16x8 blo = *reinterpret_cast<const bf16x8*>(bp + 512);
                    const int c = half * 2 + cc;
#pragma unroll
                    for (int rt = 0; rt < 2; ++rt) {
                        acc[t][rt] = __builtin_amdgcn_mfma_f32_16x16x32_bf16(alo[rt][c].v, bhi, acc[t][rt], 0, 0, 0);
                        acc[t][rt] = __builtin_amdgcn_mfma_f32_16x16x32_bf16(ahi[rt][c].v, blo, acc[t][rt], 0, 0, 0);
                        acc[t][rt] = __builtin_amdgcn_mfma_f32_16x16x32_bf16(ahi[rt][c].v, bhi, acc[t][rt], 0, 0, 0);
                    }
                }
            }
        }
        __syncthreads();   // all waves done reading B; bsh reusable per-wave

        // Epilogue: C-frags -> per-wave LDS slice (stride 136) -> coalesced
        // dwordx4 bf16 stores.  C layout: col = t*16+am, row = aq*4+r.
        unsigned short* ob = bsh + wave * 2176;   // 16 rows x 136
#pragma unroll
        for (int rt = 0; rt < 2; ++rt) {
#pragma unroll
            for (int t = 0; t < 8; ++t)
#pragma unroll
                for (int r = 0; r < 4; ++r)
                    ob[(aq * 4 + r) * 136 + t * 16 + am] = f2bu(acc[t][rt][r]);
            const int row = lane >> 2, c4 = lane & 3;
            int grow = r0w + rt * 16 + row;
            if (grow < N_NODES) {
                const uint4* srcb = reinterpret_cast<const uint4*>(ob + row * 136 + c4 * 32);
                uint4 d0 = srcb[0], d1 = srcb[1], d2 = srcb[2], d3 = srcb[3];
                bf16* base = (mat == 0)
                    ? (Q  + (size_t)grow * D)
                    : (KV + (size_t)grow * 256 + (mat == 1 ? 0 : 128));
                uint4* dst = reinterpret_cast<uint4*>(base + c4 * 32);
                dst[0] = d0; dst[1] = d1; dst[2] = d2; dst[3] = d3;
            }
        }
    }
}

// ---------------------------------------------------------------------------
// CSR build: histogram -> 3-kernel exclusive scan -> scatter  (unchanged)
// ---------------------------------------------------------------------------
__global__ __launch_bounds__(256) void hist_kernel(
    const int* __restrict__ rows, int* __restrict__ counts)
{
    int e = blockIdx.x * 256 + threadIdx.x;
    if (e < N_EDGES) atomicAdd(&counts[rows[e]], 1);
}

__global__ __launch_bounds__(256) void scan_block(
    const int* __restrict__ counts, int* __restrict__ scanned, int* __restrict__ block_sums)
{
    __shared__ int s[256];
    int tid = threadIdx.x;
    int i = blockIdx.x * 256 + tid;
    int v = (i < N_NODES) ? counts[i] : 0;
    s[tid] = v;
    __syncthreads();
#pragma unroll
    for (int off = 1; off < 256; off <<= 1) {
        int t = (tid >= off) ? s[tid - off] : 0;
        __syncthreads();
        s[tid] += t;
        __syncthreads();
    }
    if (i < N_NODES) scanned[i] = s[tid] - v;
    if (tid == 255) block_sums[blockIdx.x] = s[255];
}

__global__ __launch_bounds__(512) void scan_tops(int* __restrict__ block_sums)
{
    __shared__ int s[512];
    int tid = threadIdx.x;
    int v = (tid < NB) ? block_sums[tid] : 0;
    s[tid] = v;
    __syncthreads();
#pragma unroll
    for (int off = 1; off < 512; off <<= 1) {
        int t = (tid >= off) ? s[tid - off] : 0;
        __syncthreads();
        s[tid] += t;
        __syncthreads();
    }
    if (tid < NB) block_sums[tid] = s[tid] - v;
}

__global__ __launch_bounds__(256) void scan_add(
    int* __restrict__ scanned, const int* __restrict__ block_sums, int* __restrict__ cursor)
{
    int i = blockIdx.x * 256 + threadIdx.x;
    if (i < N_NODES) {
        int o = scanned[i] + block_sums[blockIdx.x];
        scanned[i] = o;
        cursor[i]  = o;
    }
}

__global__ __launch_bounds__(256) void scatter_kernel(
    const int* __restrict__ rows, const int* __restrict__ cols,
    int* __restrict__ cursor, int* __restrict__ csr_cols)
{
    int e = blockIdx.x * 256 + threadIdx.x;
    if (e < N_EDGES) {
        int pos = atomicAdd(&cursor[rows[e]], 1);
        csr_cols[pos] = cols[e];
    }
}

// ---------------------------------------------------------------------------
// Fused per-node attention + residual + LayerNorm.  One wave per node.
// Lane = slot*8 + head: 8 edges in flight per iteration, each edge's 8 heads
// on 8 adjacent lanes.  16-dim dot fully in-lane (no inner-loop shfl).
// ---------------------------------------------------------------------------
__global__ __launch_bounds__(256) void fused_node(
    const bf16* __restrict__ Qb, const bf16* __restrict__ KV,
    const int* __restrict__ offsets, const int* __restrict__ counts,
    const int* __restrict__ csr_cols,
    const float* __restrict__ emb,
    const float* __restrict__ gamma, const float* __restrict__ beta,
    float* __restrict__ out)
{
    int n = blockIdx.x * 4 + (threadIdx.x >> 6);
    int lane = threadIdx.x & 63;
    if (n >= N_NODES) return;
    const int head = lane & 7;
    const int slot = lane >> 3;

    // My head's 16 q values.
    const uint4* qp = reinterpret_cast<const uint4*>(Qb + (size_t)n * D + head * 16);
    uint4 qa = qp[0], qb_ = qp[1];
    float qf[16];
    ext8(qa, qf); ext8(qb_, qf + 8);

    int start = offsets[n];
    int cnt   = counts[n];

    float acc[16];
#pragma unroll
    for (int i = 0; i < 16; ++i) acc[i] = 0.f;
    float nrm = 0.f;

    for (int base = 0; base < cnt; base += 64) {
        int m = cnt - base; if (m > 64) m = 64;
        int myc = (base + lane < cnt) ? csr_cols[start + base + lane] : 0;
        for (int g = 0; g < m; g += 8) {
            int j = g + slot;
            int c = __shfl(myc, j, 64);          // c==0 (safe row) for j>=m
            const uint4* kvp = reinterpret_cast<const uint4*>(KV + (size_t)c * 256 + head * 16);
            uint4 k0 = kvp[0], k1 = kvp[1];      // 16 bf16 K
            uint4 v0 = kvp[16], v1 = kvp[17];    // 16 bf16 V (+256 B)
            float kf[16], vf[16];
            ext8(k0, kf); ext8(k1, kf + 8);
            float p = 0.f;
#pragma unroll
            for (int i = 0; i < 16; ++i) p += qf[i] * kf[i];
            float s = __expf(fminf(fmaxf(p, -10.f), 10.f));
            if (j >= m) s = 0.f;                 // mask tail lanes
            nrm += s;
            ext8(v0, vf); ext8(v1, vf + 8);
#pragma unroll
            for (int i = 0; i < 16; ++i) acc[i] += s * vf[i];
        }
    }

    // Reduce across the 8 slots (lanes l, l^8, l^16, ..., same head).
#pragma unroll
    for (int off = 8; off <= 32; off <<= 1) {
        nrm += __shfl_xor(nrm, off, 64);
#pragma unroll
        for (int i = 0; i < 16; ++i) acc[i] += __shfl_xor(acc[i], off, 64);
    }

    float w = 1.f / (nrm + 1e-8f);
    // This lane owns dims head*16 + slot*2, +1.  Static select (no dyn index).
    float a0 = 0.f, a1 = 0.f;
#pragma unroll
    for (int s2 = 0; s2 < 8; ++s2)
        if (slot == s2) { a0 = acc[2 * s2]; a1 = acc[2 * s2 + 1]; }

    int di = head * 16 + slot * 2;
    float2 e2 = *reinterpret_cast<const float2*>(emb + (size_t)n * D + di);
    float x0 = a0 * w + e2.x;
    float x1 = a1 * w + e2.y;

    float ssum = x0 + x1;
#pragma unroll
    for (int off = 32; off; off >>= 1) ssum += __shfl_xor(ssum, off, 64);
    float mean = ssum * (1.0f / 128.0f);
    float d0 = x0 - mean, d1 = x1 - mean;
    float var = d0 * d0 + d1 * d1;
#pragma unroll
    for (int off = 32; off; off >>= 1) var += __shfl_xor(var, off, 64);
    float rs = rsqrtf(var * (1.0f / 128.0f) + 1e-6f);

    float2 g2 = *reinterpret_cast<const float2*>(gamma + di);
    float2 b2 = *reinterpret_cast<const float2*>(beta + di);
    float2 o2 = make_float2(d0 * rs * g2.x + b2.x, d1 * rs * g2.y + b2.y);
    *reinterpret_cast<float2*>(out + (size_t)n * D + di) = o2;
}

// ---------------------------------------------------------------------------
extern "C" void kernel_launch(void* const* d_in, const int* in_sizes, int n_in,
                              void* d_out, int out_size, void* d_ws, size_t ws_size,
                              hipStream_t stream)
{
    const float* emb   = (const float*)d_in[0];
    const float* qW    = (const float*)d_in[1];
    const float* kW    = (const float*)d_in[2];
    const float* vW    = (const float*)d_in[3];
    const float* gamma = (const float*)d_in[4];
    const float* beta  = (const float*)d_in[5];
    const int*   eidx  = (const int*)d_in[6];
    const int*   rows  = eidx;
    const int*   cols  = eidx + N_EDGES;
    float* out = (float*)d_out;

    const size_t ND = (size_t)N_NODES * D;
    bf16* Qb = (bf16*)d_ws;                 // [N,128]
    bf16* KV = Qb + ND;                     // [N,256] interleaved K|V
    int* counts     = (int*)(KV + 2 * ND);
    int* offsets    = counts + N_NODES;
    int* cursor     = offsets + N_NODES;
    int* block_sums = cursor + N_NODES;
    int* csr_cols   = block_sums + 512;
    unsigned short* Wf = (unsigned short*)(csr_cols + N_EDGES);  // 3*32768 ushort

    hipMemsetAsync(counts, 0, (size_t)N_NODES * sizeof(int), stream);

    wf_prep<<<24, 256, 0, stream>>>(qW, kW, vW, Wf);
    qkv_mfma<<<(N_NODES + 127) / 128, 256, 0, stream>>>(emb, Wf, Qb, KV);

    hist_kernel<<<(N_EDGES + 255) / 256, 256, 0, stream>>>(rows, counts);
    scan_block<<<NB, 256, 0, stream>>>(counts, offsets, block_sums);
    scan_tops<<<1, 512, 0, stream>>>(block_sums);
    scan_add<<<NB, 256, 0, stream>>>(offsets, block_sums, cursor);
    scatter_kernel<<<(N_EDGES + 255) / 256, 256, 0, stream>>>(rows, cols, cursor, csr_cols);

    fused_node<<<(N_NODES + 3) / 4, 256, 0, stream>>>(
        Qb, KV, offsets, counts, csr_cols, emb, gamma, beta, out);
}